// Round 3
// baseline (487.604 us; speedup 1.0000x reference)
//
#include <hip/hip_runtime.h>
#include <hip/hip_bf16.h>
#include <stdint.h>

// Problem constants
#define BB 4
#define SS 2048
#define DD 1024
#define HH 16
#define DHH 128   // per-head dim after concat (2*64)

typedef __bf16 bf16x8 __attribute__((ext_vector_type(8)));
typedef __bf16 bf16x4 __attribute__((ext_vector_type(4)));
typedef float  f32x4  __attribute__((ext_vector_type(4)));

// (1/sqrt(64)) * log2(e), folded into Q at GEMM epilogue time
#define SL2E 0.180336880111186f

#if __has_builtin(__builtin_amdgcn_exp2f)
#define EXP2(x) __builtin_amdgcn_exp2f(x)
#else
#define EXP2(x) exp2f(x)
#endif

// async global->LDS, 16B per lane; LDS dest is wave-uniform base + lane*16,
// global src is per-lane (gather allowed)
#define GLOAD_LDS16(gp, lp) \
  __builtin_amdgcn_global_load_lds((const __attribute__((address_space(1))) unsigned int*)(gp), \
                                   (__attribute__((address_space(3))) unsigned int*)(lp), 16, 0, 0)

// compiler memory fence around raw s_barrier so LDS ops can't be moved across
#define SBAR() do { asm volatile("" ::: "memory"); \
                    __builtin_amdgcn_s_barrier();  \
                    asm volatile("" ::: "memory"); } while (0)

// ---------------------------------------------------------------------------
// Fused cast of x and c -> bf16 (dest xb and cb are contiguous)
__global__ void cast2_kernel(const float* __restrict__ x, const float* __restrict__ c,
                             __bf16* __restrict__ out, int n) {
    int i = (blockIdx.x * blockDim.x + threadIdx.x) * 4;
    const float* src = (i < n) ? (x + i) : (c + (i - n));
    f32x4 v = *(const f32x4*)src;
    bf16x4 o;
    o[0] = (__bf16)v[0]; o[1] = (__bf16)v[1]; o[2] = (__bf16)v[2]; o[3] = (__bf16)v[3];
    *(bf16x4*)(out + i) = o;
}

// ---------------------------------------------------------------------------
// Transpose + cast: W[K][N] fp32 -> Wt[N][K] bf16 (used for W_proj)
__global__ void transpose_cast_kernel(const float* __restrict__ in, __bf16* __restrict__ out,
                                      int K, int N) {
    __shared__ float tile[32][33];
    int n0 = blockIdx.x * 32, k0 = blockIdx.y * 32;
    int tx = threadIdx.x, ty = threadIdx.y;   // 32 x 8
    #pragma unroll
    for (int i = 0; i < 32; i += 8)
        tile[ty + i][tx] = in[(size_t)(k0 + ty + i) * N + n0 + tx];
    __syncthreads();
    #pragma unroll
    for (int i = 0; i < 32; i += 8)
        out[(size_t)(n0 + ty + i) * K + k0 + tx] = (__bf16)tile[tx][ty + i];
}

// Fused transpose+cast of the six 1024x1024 QKV weights into contiguous dst
// Order: Wq_x, Wk_x, Wv_x, Wq_c, Wk_c, Wv_c  (Q,K adjacent per input for fusion)
__global__ void transpose6_kernel(const float* s0, const float* s1, const float* s2,
                                  const float* s3, const float* s4, const float* s5,
                                  __bf16* __restrict__ dst) {
    const float* srcs[6] = {s0, s1, s2, s3, s4, s5};
    const float* __restrict__ in = srcs[blockIdx.z];
    __bf16* __restrict__ out = dst + (size_t)blockIdx.z * 1024 * 1024;
    __shared__ float tile[32][33];
    int n0 = blockIdx.x * 32, k0 = blockIdx.y * 32;
    int tx = threadIdx.x, ty = threadIdx.y;   // 32 x 8
    #pragma unroll
    for (int i = 0; i < 32; i += 8)
        tile[ty + i][tx] = in[(size_t)(k0 + ty + i) * 1024 + n0 + tx];
    __syncthreads();
    #pragma unroll
    for (int i = 0; i < 32; i += 8)
        out[(size_t)(n0 + ty + i) * 1024 + k0 + tx] = (__bf16)tile[tx][ty + i];
}

// ---------------------------------------------------------------------------
// 256x256 deep-pipelined GEMM: C = A @ Bt^T (bf16, both contiguous in K).
// 512 threads = 8 waves (2 rows x 4 cols), per-wave output 128x64 (acc 8x4).
// BK=32; LDS = ring of 4 buffers x (A 16KB + B 16KB) = 128 KB.
// Staging runs 3 tiles ahead via global_load_lds; tile boundary uses COUNTED
// s_waitcnt vmcnt(8) (never drains to 0 in-loop). Raw s_barrier, setprio(1)
// around MFMA. LDS chunk swizzle chunk'=chunk^((row>>2)&3) applied both-sides
// (pre-swizzled global source, swizzled ds_read).
// XCD swizzle (T1, bijective since nwg%8==0 for all our grids): each XCD
// gets a contiguous logical chunk -> B-slab L2 reuse.
template <int EPI>
__global__ __launch_bounds__(512, 2)
void gemm256_kernel(const __bf16* __restrict__ A0, const __bf16* __restrict__ A1,
                    const __bf16* __restrict__ B0, const __bf16* __restrict__ B1,
                    int K, void* __restrict__ outp, const float* __restrict__ bias) {
    const int z = blockIdx.z;
    const __bf16* __restrict__ A  = z ? A1 : A0;
    const __bf16* __restrict__ Bt = z ? B1 : B0;
    const int qkv_off = z * 64;

    __shared__ __align__(16) char smem[131072];   // 4 x (A 16KB @0 + B 16KB @16384)

    const int tid = threadIdx.x;
    const int wave = tid >> 6, lane = tid & 63;
    const int l15 = lane & 15, quad = lane >> 4;
    const int wr = wave >> 2, wc = wave & 3;      // wave -> (row half, col quarter)

    // XCD-aware block remap (bijective: nwg per z is a multiple of 8)
    const int gx = gridDim.x;
    const int nwg = gx * gridDim.y;
    const int hwl = blockIdx.y * gx + blockIdx.x;
    const int lg  = (hwl & 7) * (nwg >> 3) + (hwl >> 3);
    const int m0 = (lg % gx) * 256, n0 = (lg / gx) * 256;

    // ---- staging: thread tid covers (r = j*128 + tid/4, chunk = tid&3), j=0,1
    // global source chunk is pre-swizzled: c_src = (tid&3) ^ ((r>>2)&3); since
    // j*128>>2 is 0 mod 4, c_src = (tid&3) ^ ((tid>>4)&3) for both j.
    const int rA = tid >> 2;
    const int cs = (tid & 3) ^ ((tid >> 4) & 3);
    const __bf16* aS0 = A  + (size_t)(m0 + rA) * K + cs * 8;
    const __bf16* aS1 = aS0 + (size_t)128 * K;
    const __bf16* bS0 = Bt + (size_t)(n0 + rA) * K + cs * 8;
    const __bf16* bS1 = bS0 + (size_t)128 * K;
    const int ldsA = wave * 1024;            // + j*8192 + buf*32768 (lane*16 by HW)
    const int ldsB = 16384 + wave * 1024;

    // ---- ds_read bases: row r in tile, byte = r*64 + (quad ^ ((r>>2)&3))*16.
    // For r = (wr*128|wc*64) + mi*16 + l15 the swizzle term reduces to l15>>2.
    const int swz = ((quad ^ (l15 >> 2)) & 3) * 16;
    const int ra = (wr * 128 + l15) * 64 + swz;            // + mi*1024 + buf
    const int rb = 16384 + (wc * 64 + l15) * 64 + swz;     // + ni*1024 + buf

    f32x4 acc[8][4] = {};
    const int NT = K >> 5;

    #define STAGE_A(tt) do { const int bo_ = ((tt) & 3) * 32768; \
        GLOAD_LDS16(aS0 + (size_t)(tt) * 32, smem + bo_ + ldsA); \
        GLOAD_LDS16(aS1 + (size_t)(tt) * 32, smem + bo_ + ldsA + 8192); } while (0)
    #define STAGE_B(tt) do { const int bo_ = ((tt) & 3) * 32768; \
        GLOAD_LDS16(bS0 + (size_t)(tt) * 32, smem + bo_ + ldsB); \
        GLOAD_LDS16(bS1 + (size_t)(tt) * 32, smem + bo_ + ldsB + 8192); } while (0)

    // prologue: stage tiles 0..2 (12 loads), wait for tile 0 (8 younger in flight)
    STAGE_A(0); STAGE_B(0);
    STAGE_A(1); STAGE_B(1);
    STAGE_A(2); STAGE_B(2);
    asm volatile("s_waitcnt vmcnt(8)" ::: "memory");
    SBAR();

    for (int t = 0; t < NT; ++t) {
        const int co = (t & 3) * 32768;
        bf16x8 af[4], bfr[4];
        // ---------------- phase 1: mi 0-3 x ni 0-3 ----------------
        #pragma unroll
        for (int i = 0; i < 4; ++i) af[i]  = *(const bf16x8*)(smem + co + ra + i * 1024);
        #pragma unroll
        for (int i = 0; i < 4; ++i) bfr[i] = *(const bf16x8*)(smem + co + rb + i * 1024);
        if (t + 3 < NT) STAGE_A(t + 3);
        SBAR();
        __builtin_amdgcn_s_setprio(1);
        #pragma unroll
        for (int mi = 0; mi < 4; ++mi)
            #pragma unroll
            for (int ni = 0; ni < 4; ++ni)
                acc[mi][ni] = __builtin_amdgcn_mfma_f32_16x16x32_bf16(af[mi], bfr[ni], acc[mi][ni], 0, 0, 0);
        __builtin_amdgcn_s_setprio(0);
        SBAR();
        // ---------------- phase 2: mi 4-7 x ni 0-3 ----------------
        #pragma unroll
        for (int i = 0; i < 4; ++i) af[i] = *(const bf16x8*)(smem + co + ra + (4 + i) * 1024);
        if (t + 3 < NT) STAGE_B(t + 3);
        SBAR();
        __builtin_amdgcn_s_setprio(1);
        #pragma unroll
        for (int mi = 0; mi < 4; ++mi)
            #pragma unroll
            for (int ni = 0; ni < 4; ++ni)
                acc[4 + mi][ni] = __builtin_amdgcn_mfma_f32_16x16x32_bf16(af[mi], bfr[ni], acc[4 + mi][ni], 0, 0, 0);
        __builtin_amdgcn_s_setprio(0);
        // counted wait: tile t+1's 4 loads landed; t+2/t+3 stay in flight
        if (t < NT - 3)       asm volatile("s_waitcnt vmcnt(8)" ::: "memory");
        else if (t == NT - 3) asm volatile("s_waitcnt vmcnt(4)" ::: "memory");
        else if (t == NT - 2) asm volatile("s_waitcnt vmcnt(0)" ::: "memory");
        SBAR();
    }
    #undef STAGE_A
    #undef STAGE_B

    const size_t nQKV = (size_t)BB * HH * SS * DHH;
    #pragma unroll
    for (int mi = 0; mi < 8; ++mi) {
        #pragma unroll
        for (int ni = 0; ni < 4; ++ni) {
            #pragma unroll
            for (int rr = 0; rr < 4; ++rr) {
                int m = m0 + wr * 128 + mi * 16 + quad * 4 + rr;
                int n = n0 + wc * 64 + ni * 16 + l15;
                if (EPI == 1) {
                    float* o = (float*)outp;
                    o[(size_t)m * 1024 + n] = acc[mi][ni][rr] + bias[n];
                } else if (EPI == 2) {
                    int h = m >> 6, dl = m & 63;
                    int b = n >> 11, s = n & (SS - 1);
                    __bf16* vt = (__bf16*)outp;
                    vt[(((size_t)b * HH + h) * DHH + dl + qkv_off) * SS + s] = (__bf16)acc[mi][ni][rr];
                } else {  // EPI 4
                    int b = m >> 11, s = m & (SS - 1);
                    int n1 = n & 1023;
                    int h = n1 >> 6, d = (n1 & 63) + qkv_off;
                    if (n < 1024) {
                        __bf16* q = (__bf16*)outp;
                        q[(((size_t)b * HH + h) * SS + s) * DHH + d] = (__bf16)(acc[mi][ni][rr] * SL2E);
                    } else {
                        int dsw = (((d >> 3) ^ (s & 15)) << 3) | (d & 7);
                        __bf16* kq = (__bf16*)outp + nQKV;
                        kq[(((size_t)b * HH + h) * SS + s) * DHH + dsw] = (__bf16)acc[mi][ni][rr];
                    }
                }
            }
        }
    }
}

// ---------------------------------------------------------------------------
// Flash attention (no-max softmax; Q pre-scaled so p = exp2(s) directly).
// Q: [bh][S][128]; Kg: [bh][S][128] chunk-swizzled (chunk^(s&15));
// Vg: [bh][128][S] (V^T); O: [B][S][H*128] bf16.
// Launched as TWO 512-block halves (bh0 = 0, 32) with a bh->XCD grouping
// remap: all 16 mt-blocks of one bh get linear ids congruent mod 8, landing
// on one XCD (round-robin dispatch heuristic) -> that XCD's L2 serves K/V
// re-reads (1 MB per bh; ~4 bh resident per 4 MB XCD L2). Perf-only remap.
// 4 waves; Q tile 128; KV tile 64 as two 32-kv halves; P round-trip is
// intra-wave (no mid-tile barriers); K/V staging double-buffered, 1
// __syncthreads per kt.
#define LDS_BUFSZ 32768
#define LDS_VT    16384
#define LDS_PS    65536
__global__ __launch_bounds__(256, 2)
void attn_kernel(const __bf16* __restrict__ Q, const __bf16* __restrict__ Kg,
                 const __bf16* __restrict__ Vg, __bf16* __restrict__ O, int bh0) {
    __shared__ __align__(16) char smem[73728];

    const int t = threadIdx.x;
    const int wave = t >> 6, lane = t & 63;
    const int l15 = lane & 15, quad = lane >> 4;

    // bh->XCD grouping decode (bijective over 512 blocks x 32 bh x 16 mt)
    const int lin = blockIdx.x;              // 0..511
    const int slot = lin >> 3, xcd = lin & 7;
    const int mt = slot & 15;                // 0..15, 128-row Q tile
    const int bh = bh0 + ((slot >> 4) << 3) + xcd;

    const int b = bh >> 4, h = bh & 15;
    const size_t base  = (size_t)bh * SS * DHH;
    const size_t vbase = (size_t)bh * DHH * SS;

    // K B-frag: addr = l15*256 + swz-chunk*16  (+4096*nl + 8192*hf + buf at use)
    int kaddr[4];
    #pragma unroll
    for (int kst = 0; kst < 4; ++kst)
        kaddr[kst] = l15 * 256 + (((4 * kst + quad) ^ l15) & 15) * 16;
    // Vt B-frag: row d = ds*16+l15 (imm 2048*ds), k-block = hf
    int vaddr[2];
    #pragma unroll
    for (int hf = 0; hf < 2; ++hf)
        vaddr[hf] = LDS_VT + l15 * 128 + (((4 * hf + quad) ^ (l15 & 7)) & 7) * 16;
    // Ps write base per nl: row = 32w+16ms+4q+rr -> +1024*ms+64*rr imm
    int pw[2];
    #pragma unroll
    for (int nl = 0; nl < 2; ++nl)
        pw[nl] = LDS_PS + (wave * 32 + quad * 4) * 64 +
                 (((2 * nl + (l15 >> 3)) ^ quad) & 3) * 16 + (l15 & 7) * 2;
    // Ps A-frag read base: row = 32w+16ms+l15 -> +1024*ms imm
    const int par = LDS_PS + (wave * 32 + l15) * 64 + ((quad ^ (l15 >> 2)) & 3) * 16;

    // staging source pointers (mt-independent)
    const __bf16* kstage = Kg + base + (size_t)wave * 2048 + lane * 8;
    const __bf16* vstage = Vg + vbase + (size_t)(wave * 32 + (lane >> 3)) * SS
                           + ((lane & 7) ^ ((lane >> 3) & 7)) * 8;

    // stage KV tile kt into buffer at byte offset bo (0 or LDS_BUFSZ)
    #define STAGE_KV(kt_, bo_) do { \
        _Pragma("unroll") \
        for (int i_ = 0; i_ < 4; ++i_) \
            GLOAD_LDS16(kstage + (size_t)(kt_) * 8192 + i_ * 512, \
                        smem + (bo_) + wave * 4096 + i_ * 1024); \
        _Pragma("unroll") \
        for (int i_ = 0; i_ < 4; ++i_) \
            GLOAD_LDS16(vstage + (kt_) * 64 + (size_t)i_ * 8 * SS, \
                        smem + (bo_) + LDS_VT + wave * 4096 + i_ * 1024); \
    } while (0)

    // Q fragments (A-operand), rows mt*128 + wave*32 + ms*16 + l15
    bf16x8 qf[2][4];
    #pragma unroll
    for (int ms = 0; ms < 2; ++ms) {
        int row = mt * 128 + wave * 32 + ms * 16 + l15;
        #pragma unroll
        for (int kst = 0; kst < 4; ++kst)
            qf[ms][kst] = *(const bf16x8*)(Q + base + (size_t)row * DHH + kst * 32 + quad * 8);
    }

    f32x4 oacc[2][8] = {};
    float li_[2][4] = {};

    STAGE_KV(0, 0);
    __syncthreads();   // drain stage(0)

    for (int kt = 0; kt < SS / 64; ++kt) {
        const int co = (kt & 1) * LDS_BUFSZ;
        if (kt + 1 < SS / 64) STAGE_KV(kt + 1, co ^ LDS_BUFSZ);

        #pragma unroll
        for (int hf = 0; hf < 2; ++hf) {
            // ---- QK for kv half hf (ns = 2hf, 2hf+1) ----
            f32x4 sx[2][2] = {};
            __builtin_amdgcn_s_setprio(1);
            #pragma unroll
            for (int kst = 0; kst < 4; ++kst) {
                bf16x8 kf0 = *(const bf16x8*)(smem + co + kaddr[kst] + 8192 * hf);
                bf16x8 kf1 = *(const bf16x8*)(smem + co + kaddr[kst] + 8192 * hf + 4096);
                sx[0][0] = __builtin_amdgcn_mfma_f32_16x16x32_bf16(qf[0][kst], kf0, sx[0][0], 0, 0, 0);
                sx[1][0] = __builtin_amdgcn_mfma_f32_16x16x32_bf16(qf[1][kst], kf0, sx[1][0], 0, 0, 0);
                sx[0][1] = __builtin_amdgcn_mfma_f32_16x16x32_bf16(qf[0][kst], kf1, sx[0][1], 0, 0, 0);
                sx[1][1] = __builtin_amdgcn_mfma_f32_16x16x32_bf16(qf[1][kst], kf1, sx[1][1], 0, 0, 0);
            }
            __builtin_amdgcn_s_setprio(0);
            // ---- p = exp2(s), row-sum partials ----
            #pragma unroll
            for (int ms = 0; ms < 2; ++ms)
                #pragma unroll
                for (int nl = 0; nl < 2; ++nl)
                    #pragma unroll
                    for (int rr = 0; rr < 4; ++rr) {
                        float p = EXP2(sx[ms][nl][rr]);
                        li_[ms][rr] += p;
                        sx[ms][nl][rr] = p;
                    }

            // ---- P-half -> LDS (intra-wave scratch, no barrier needed) ----
            #pragma unroll
            for (int ms = 0; ms < 2; ++ms)
                #pragma unroll
                for (int nl = 0; nl < 2; ++nl)
                    #pragma unroll
                    for (int rr = 0; rr < 4; ++rr)
                        *(__bf16*)(smem + pw[nl] + 1024 * ms + 64 * rr)
                            = (__bf16)sx[ms][nl][rr];

            // ---- O += P-half @ V-half ----
            bf16x8 pa0 = *(const bf16x8*)(smem + par);
            bf16x8 pa1 = *(const bf16x8*)(smem + par + 1024);
            __builtin_amdgcn_s_setprio(1);
            #pragma unroll
            for (int ds = 0; ds < 8; ++ds) {
                bf16x8 vf = *(const bf16x8*)(smem + co + vaddr[hf] + 2048 * ds);
                oacc[0][ds] = __builtin_amdgcn_mfma_f32_16x16x32_bf16(pa0, vf, oacc[0][ds], 0, 0, 0);
                oacc[1][ds] = __builtin_amdgcn_mfma_f32_16x16x32_bf16(pa1, vf, oacc[1][ds], 0, 0, 0);
            }
            __builtin_amdgcn_s_setprio(0);
        }
        // one barrier per kt: drains stage(kt+1) DMA (vmcnt) and orders all-wave
        // reads of buf(kt) before stage(kt+2) overwrites it next iteration
        __syncthreads();
    }
    #undef STAGE_KV

    // epilogue: reduce row-sums across the 16 lanes sharing a row
    #pragma unroll
    for (int ms = 0; ms < 2; ++ms)
        #pragma unroll
        for (int rr = 0; rr < 4; ++rr) {
            float v = li_[ms][rr];
            v += __shfl_xor(v, 1);
            v += __shfl_xor(v, 2);
            v += __shfl_xor(v, 4);
            v += __shfl_xor(v, 8);
            li_[ms][rr] = 1.f / v;
        }

    #pragma unroll
    for (int ms = 0; ms < 2; ++ms)
        #pragma unroll
        for (int rr = 0; rr < 4; ++rr) {
            int s = mt * 128 + wave * 32 + ms * 16 + quad * 4 + rr;
            size_t ob = ((size_t)b * SS + s) * (HH * DHH) + (size_t)h * DHH;
            #pragma unroll
            for (int ds = 0; ds < 8; ++ds)
                O[ob + ds * 16 + l15] = (__bf16)(oacc[ms][ds][rr] * li_[ms][rr]);
        }
}

// ---------------------------------------------------------------------------
extern "C" void kernel_launch(void* const* d_in, const int* in_sizes, int n_in,
                              void* d_out, int out_size, void* d_ws, size_t ws_size,
                              hipStream_t stream) {
    const float* x      = (const float*)d_in[0];
    const float* c      = (const float*)d_in[1];
    const float* Wq_x   = (const float*)d_in[2];
    const float* Wk_x   = (const float*)d_in[3];
    const float* Wv_x   = (const float*)d_in[4];
    const float* Wq_c   = (const float*)d_in[5];
    const float* Wk_c   = (const float*)d_in[6];
    const float* Wv_c   = (const float*)d_in[7];
    const float* W_proj = (const float*)d_in[8];
    const float* b_proj = (const float*)d_in[9];

    const size_t nXC  = (size_t)BB * SS * DD;
    const size_t nW   = (size_t)DD * DD;
    const size_t nWP  = (size_t)(2 * HH * 64) * DD;
    const size_t nQKV = (size_t)BB * HH * SS * DHH;

    __bf16* ws  = (__bf16*)d_ws;
    __bf16* xb  = ws;
    __bf16* cb  = xb + nXC;
    __bf16* wt0 = cb + nXC;          // [Wq_x; Wk_x; Wv_x; Wq_c; Wk_c; Wv_c]^T contiguous
    __bf16* wt2 = wt0 + 2 * nW;      // Wv_x^T
    __bf16* wt3 = wt0 + 3 * nW;      // Wq_c^T (c's Q,K pair start)
    __bf16* wt5 = wt0 + 5 * nW;      // Wv_c^T
    __bf16* wtp = wt0 + 6 * nW;      // W_proj^T [1024][2048]
    __bf16* Qb  = wtp + nWP;
    __bf16* Kb  = Qb + nQKV;         // MUST stay at Qb + nQKV (EPI4 assumes it)
    __bf16* Vb  = Kb + nQKV;         // [B*H][128][S] pre-transposed
    __bf16* Ob  = xb;                // alias x/c region (dead after QKV GEMMs)

    cast2_kernel<<<(int)(2 * nXC / 1024), 256, 0, stream>>>(x, c, xb, (int)nXC);

    transpose6_kernel<<<dim3(32, 32, 6), dim3(32, 8), 0, stream>>>(
        Wq_x, Wk_x, Wv_x, Wq_c, Wk_c, Wv_c, wt0);
    transpose_cast_kernel<<<dim3(32, 64), dim3(32, 8), 0, stream>>>(W_proj, wtp, 2048, 1024);

    // z-batched fused Q+K GEMMs (M=8192, N=2048, K=1024): z=0 x-path, z=1 c-path
    gemm256_kernel<4><<<dim3(32, 8, 2), 512, 0, stream>>>(xb, cb, wt0, wt3, 1024, Qb, nullptr);
    // z-batched V GEMMs (A = Wv^T, B = activations) -> V^T [bh][d][s]
    gemm256_kernel<2><<<dim3(4, 32, 2), 512, 0, stream>>>(wt2, wt5, xb, cb, 1024, Vb, nullptr);

    // attention (writes Ob = [B,S,H*128] bf16): two 512-block halves with
    // bh->XCD grouping (diagnostic: also lets GEMM counters surface in top-5)
    attn_kernel<<<dim3(512), 256, 0, stream>>>(Qb, Kb, Vb, Ob, 0);
    attn_kernel<<<dim3(512), 256, 0, stream>>>(Qb, Kb, Vb, Ob, 32);

    // projection (M=8192, K=2048, N=1024) + bias -> fp32 out
    gemm256_kernel<1><<<dim3(32, 4, 1), 512, 0, stream>>>(Ob, nullptr, wtp, nullptr, 2048, d_out, b_proj);
}

// Round 6
// 447.513 us; speedup vs baseline: 1.0896x; 1.0896x over previous
//
#include <hip/hip_runtime.h>
#include <hip/hip_bf16.h>
#include <stdint.h>

// Problem constants
#define BB 4
#define SS 2048
#define DD 1024
#define HH 16
#define DHH 128   // per-head dim after concat (2*64)

typedef __bf16 bf16x8 __attribute__((ext_vector_type(8)));
typedef __bf16 bf16x4 __attribute__((ext_vector_type(4)));
typedef float  f32x4  __attribute__((ext_vector_type(4)));

// (1/sqrt(64)) * log2(e), folded into Q at GEMM epilogue time
#define SL2E 0.180336880111186f

#if __has_builtin(__builtin_amdgcn_exp2f)
#define EXP2(x) __builtin_amdgcn_exp2f(x)
#else
#define EXP2(x) exp2f(x)
#endif

// async global->LDS, 16B per lane; LDS dest is wave-uniform base + lane*16,
// global src is per-lane (gather allowed)
#define GLOAD_LDS16(gp, lp) \
  __builtin_amdgcn_global_load_lds((const __attribute__((address_space(1))) unsigned int*)(gp), \
                                   (__attribute__((address_space(3))) unsigned int*)(lp), 16, 0, 0)

// compiler memory fence around raw s_barrier so LDS ops can't be moved across
#define SBAR() do { asm volatile("" ::: "memory"); \
                    __builtin_amdgcn_s_barrier();  \
                    asm volatile("" ::: "memory"); } while (0)

#define MFMA_BF16(a, b, c) __builtin_amdgcn_mfma_f32_16x16x32_bf16((a), (b), (c), 0, 0, 0)

// ---------------------------------------------------------------------------
// Fused cast of x and c -> bf16 (dest xb and cb are contiguous)
__global__ void cast2_kernel(const float* __restrict__ x, const float* __restrict__ c,
                             __bf16* __restrict__ out, int n) {
    int i = (blockIdx.x * blockDim.x + threadIdx.x) * 4;
    const float* src = (i < n) ? (x + i) : (c + (i - n));
    f32x4 v = *(const f32x4*)src;
    bf16x4 o;
    o[0] = (__bf16)v[0]; o[1] = (__bf16)v[1]; o[2] = (__bf16)v[2]; o[3] = (__bf16)v[3];
    *(bf16x4*)(out + i) = o;
}

// ---------------------------------------------------------------------------
// Transpose + cast: W[K][N] fp32 -> Wt[N][K] bf16 (used for W_proj)
__global__ void transpose_cast_kernel(const float* __restrict__ in, __bf16* __restrict__ out,
                                      int K, int N) {
    __shared__ float tile[32][33];
    int n0 = blockIdx.x * 32, k0 = blockIdx.y * 32;
    int tx = threadIdx.x, ty = threadIdx.y;   // 32 x 8
    #pragma unroll
    for (int i = 0; i < 32; i += 8)
        tile[ty + i][tx] = in[(size_t)(k0 + ty + i) * N + n0 + tx];
    __syncthreads();
    #pragma unroll
    for (int i = 0; i < 32; i += 8)
        out[(size_t)(n0 + ty + i) * K + k0 + tx] = (__bf16)tile[tx][ty + i];
}

// Fused transpose+cast of the six 1024x1024 QKV weights into contiguous dst
// Order: Wq_x, Wk_x, Wv_x, Wq_c, Wk_c, Wv_c  (Q,K adjacent per input for fusion)
__global__ void transpose6_kernel(const float* s0, const float* s1, const float* s2,
                                  const float* s3, const float* s4, const float* s5,
                                  __bf16* __restrict__ dst) {
    const float* srcs[6] = {s0, s1, s2, s3, s4, s5};
    const float* __restrict__ in = srcs[blockIdx.z];
    __bf16* __restrict__ out = dst + (size_t)blockIdx.z * 1024 * 1024;
    __shared__ float tile[32][33];
    int n0 = blockIdx.x * 32, k0 = blockIdx.y * 32;
    int tx = threadIdx.x, ty = threadIdx.y;   // 32 x 8
    #pragma unroll
    for (int i = 0; i < 32; i += 8)
        tile[ty + i][tx] = in[(size_t)(k0 + ty + i) * 1024 + n0 + tx];
    __syncthreads();
    #pragma unroll
    for (int i = 0; i < 32; i += 8)
        out[(size_t)(n0 + ty + i) * 1024 + k0 + tx] = (__bf16)tile[tx][ty + i];
}

// ---------------------------------------------------------------------------
// 256x256 pipelined GEMM: C = A @ Bt^T (bf16, both contiguous in K).
// 512 threads = 8 waves (2x4), per-wave 128x64 output (acc 8x4).
// BK=32; LDS ring of 4 x 32KB; staging 3 tiles ahead (global_load_lds).
// SCHEDULE: fragments are read ONE PHASE AHEAD of their MFMA, so LDS service
// overlaps the previous MFMA cluster:
//   ph1: read afB(4, this tile mi4-7) | stage A(t+3) | SBAR | MFMA afc[u]*bfc[u]
//   ph2: stage B(t+3) | counted vmcnt(8) | SBAR | read set[u^1](8, tile t+1)
//        | MFMA afB*bfc[u]
// Next-tile reads come AFTER the barrier that follows vmcnt (cross-wave DMA
// visibility). Register ping-pong sets afc/bfc[2] are static-indexed via the
// unrolled u loop. Compiler emits the counted lgkm waits automatically.
// vmcnt never drains to 0 until the 2-tile epilogue.
template <int EPI>
__global__ __launch_bounds__(512, 2)
void gemm256_kernel(const __bf16* __restrict__ A0, const __bf16* __restrict__ A1,
                    const __bf16* __restrict__ B0, const __bf16* __restrict__ B1,
                    int K, void* __restrict__ outp, const float* __restrict__ bias) {
    const int z = blockIdx.z;
    const __bf16* __restrict__ A  = z ? A1 : A0;
    const __bf16* __restrict__ Bt = z ? B1 : B0;
    const int qkv_off = z * 64;

    __shared__ __align__(16) char smem[131072];   // 4 x (A 16KB @0 + B 16KB @16384)

    const int tid = threadIdx.x;
    const int wave = tid >> 6, lane = tid & 63;
    const int l15 = lane & 15, quad = lane >> 4;
    const int wr = wave >> 2, wc = wave & 3;      // wave -> (row half, col quarter)

    // XCD-aware block remap (bijective: nwg per z is a multiple of 8)
    const int gx = gridDim.x;
    const int nwg = gx * gridDim.y;
    const int hwl = blockIdx.y * gx + blockIdx.x;
    const int lg  = (hwl & 7) * (nwg >> 3) + (hwl >> 3);
    const int m0 = (lg % gx) * 256, n0 = (lg / gx) * 256;

    // staging: thread tid covers (r = j*128 + tid/4, chunk = tid&3), j=0,1
    // global source chunk pre-swizzled: c_src = (tid&3) ^ ((r>>2)&3)
    const int rA = tid >> 2;
    const int cs = (tid & 3) ^ ((tid >> 4) & 3);
    const __bf16* aS0 = A  + (size_t)(m0 + rA) * K + cs * 8;
    const __bf16* aS1 = aS0 + (size_t)128 * K;
    const __bf16* bS0 = Bt + (size_t)(n0 + rA) * K + cs * 8;
    const __bf16* bS1 = bS0 + (size_t)128 * K;
    const int ldsA = wave * 1024;            // + j*8192 + buf*32768 (lane*16 by HW)
    const int ldsB = 16384 + wave * 1024;

    // ds_read bases: row r, byte = r*64 + ((quad ^ ((r>>2)&3))&3)*16
    const int swz = ((quad ^ (l15 >> 2)) & 3) * 16;
    const int ra = (wr * 128 + l15) * 64 + swz;            // + mi*1024 + buf
    const int rb = 16384 + (wc * 64 + l15) * 64 + swz;     // + ni*1024 + buf

    f32x4 acc[8][4] = {};
    bf16x8 afc[2][4], bfc[2][4], afB[4];
    const int NT = K >> 5;

    #define STAGE_A(tt) do { const int bo_ = ((tt) & 3) * 32768; \
        GLOAD_LDS16(aS0 + (size_t)(tt) * 32, smem + bo_ + ldsA); \
        GLOAD_LDS16(aS1 + (size_t)(tt) * 32, smem + bo_ + ldsA + 8192); } while (0)
    #define STAGE_B(tt) do { const int bo_ = ((tt) & 3) * 32768; \
        GLOAD_LDS16(bS0 + (size_t)(tt) * 32, smem + bo_ + ldsB); \
        GLOAD_LDS16(bS1 + (size_t)(tt) * 32, smem + bo_ + ldsB + 8192); } while (0)

    // prologue: stage tiles 0..2; wait tile 0 (8 younger in flight); read set0
    STAGE_A(0); STAGE_B(0);
    STAGE_A(1); STAGE_B(1);
    STAGE_A(2); STAGE_B(2);
    asm volatile("s_waitcnt vmcnt(8)" ::: "memory");
    SBAR();
    #pragma unroll
    for (int i = 0; i < 4; ++i) afc[0][i] = *(const bf16x8*)(smem + ra + i * 1024);
    #pragma unroll
    for (int i = 0; i < 4; ++i) bfc[0][i] = *(const bf16x8*)(smem + rb + i * 1024);

    for (int tp = 0; tp < NT / 2; ++tp) {
        #pragma unroll
        for (int u = 0; u < 2; ++u) {
            const int t = 2 * tp + u;
            const int co = (t & 3) * 32768;
            const int cn = ((t + 1) & 3) * 32768;
            // ---------------- phase 1 ----------------
            #pragma unroll
            for (int i = 0; i < 4; ++i)
                afB[i] = *(const bf16x8*)(smem + co + ra + (4 + i) * 1024);
            if (t + 3 < NT) STAGE_A(t + 3);
            SBAR();
            __builtin_amdgcn_s_setprio(1);
            #pragma unroll
            for (int mi = 0; mi < 4; ++mi)
                #pragma unroll
                for (int ni = 0; ni < 4; ++ni)
                    acc[mi][ni] = MFMA_BF16(afc[u][mi], bfc[u][ni], acc[mi][ni]);
            __builtin_amdgcn_s_setprio(0);
            // ---------------- phase 2 ----------------
            if (t + 3 < NT) STAGE_B(t + 3);
            if (t < NT - 3)       asm volatile("s_waitcnt vmcnt(8)" ::: "memory");
            else if (t == NT - 3) asm volatile("s_waitcnt vmcnt(4)" ::: "memory");
            else if (t == NT - 2) asm volatile("s_waitcnt vmcnt(0)" ::: "memory");
            SBAR();
            #pragma unroll
            for (int i = 0; i < 4; ++i)
                afc[u ^ 1][i] = *(const bf16x8*)(smem + cn + ra + i * 1024);
            #pragma unroll
            for (int i = 0; i < 4; ++i)
                bfc[u ^ 1][i] = *(const bf16x8*)(smem + cn + rb + i * 1024);
            __builtin_amdgcn_s_setprio(1);
            #pragma unroll
            for (int mi = 0; mi < 4; ++mi)
                #pragma unroll
                for (int ni = 0; ni < 4; ++ni)
                    acc[4 + mi][ni] = MFMA_BF16(afB[mi], bfc[u][ni], acc[4 + mi][ni]);
            __builtin_amdgcn_s_setprio(0);
        }
    }
    #undef STAGE_A
    #undef STAGE_B

    const size_t nQKV = (size_t)BB * HH * SS * DHH;
    #pragma unroll
    for (int mi = 0; mi < 8; ++mi) {
        #pragma unroll
        for (int ni = 0; ni < 4; ++ni) {
            #pragma unroll
            for (int rr = 0; rr < 4; ++rr) {
                int m = m0 + wr * 128 + mi * 16 + quad * 4 + rr;
                int n = n0 + wc * 64 + ni * 16 + l15;
                if (EPI == 2) {
                    int h = m >> 6, dl = m & 63;
                    int b = n >> 11, s = n & (SS - 1);
                    __bf16* vt = (__bf16*)outp;
                    vt[(((size_t)b * HH + h) * DHH + dl + qkv_off) * SS + s] = (__bf16)acc[mi][ni][rr];
                } else {  // EPI 4
                    int b = m >> 11, s = m & (SS - 1);
                    int n1 = n & 1023;
                    int h = n1 >> 6, d = (n1 & 63) + qkv_off;
                    if (n < 1024) {
                        __bf16* q = (__bf16*)outp;
                        q[(((size_t)b * HH + h) * SS + s) * DHH + d] = (__bf16)(acc[mi][ni][rr] * SL2E);
                    } else {
                        int dsw = (((d >> 3) ^ (s & 15)) << 3) | (d & 7);
                        __bf16* kq = (__bf16*)outp + nQKV;
                        kq[(((size_t)b * HH + h) * SS + s) * DHH + dsw] = (__bf16)acc[mi][ni][rr];
                    }
                }
            }
        }
    }
}

// ---------------------------------------------------------------------------
// Projection GEMM (EPI1 replacement): C = A @ Bt^T + bias, fp32 out.
// Tile 256x128 -> grid 32x8 = 256 blocks (full chip; old 256x256 gave 128).
// 512 threads = 8 waves (4x2), per-wave 64x64 (acc 4x4 = 64 regs).
// Same pipelined pattern, single phase per tile: stage(t+3) | vmcnt(6) |
// SBAR | read next-tile set (8) | MFMA current set (16). Ring-4 x 24KB LDS.
__global__ __launch_bounds__(512, 2)
void gemm_proj_kernel(const __bf16* __restrict__ A, const __bf16* __restrict__ Bt,
                      int K, float* __restrict__ outp, const float* __restrict__ bias) {
    __shared__ __align__(16) char smem[98304];    // 4 x (A 16KB @0 + B 8KB @16384)

    const int tid = threadIdx.x;
    const int wave = tid >> 6, lane = tid & 63;
    const int l15 = lane & 15, quad = lane >> 4;
    const int wr = wave >> 1, wc = wave & 1;      // 4 row-strips x 2 col-halves

    // XCD-aware remap (nwg = 256, multiple of 8)
    const int gx = gridDim.x;
    const int nwg = gx * gridDim.y;
    const int hwl = blockIdx.y * gx + blockIdx.x;
    const int lg  = (hwl & 7) * (nwg >> 3) + (hwl >> 3);
    const int m0 = (lg % gx) * 256, n0 = (lg / gx) * 128;

    const int rA = tid >> 2;
    const int cs = (tid & 3) ^ ((tid >> 4) & 3);
    const __bf16* aS0 = A  + (size_t)(m0 + rA) * K + cs * 8;
    const __bf16* aS1 = aS0 + (size_t)128 * K;
    const __bf16* bS0 = Bt + (size_t)(n0 + rA) * K + cs * 8;   // rA < 128 covers all B rows
    const int ldsA = wave * 1024;
    const int ldsB = 16384 + wave * 1024;

    const int swz = ((quad ^ (l15 >> 2)) & 3) * 16;
    const int ra = (wr * 64 + l15) * 64 + swz;             // + mi*1024 + buf
    const int rb = 16384 + (wc * 64 + l15) * 64 + swz;     // + ni*1024 + buf

    f32x4 acc[4][4] = {};
    bf16x8 afc[2][4], bfc[2][4];
    const int NT = K >> 5;

    #define STAGE_P(tt) do { const int bo_ = ((tt) & 3) * 24576; \
        GLOAD_LDS16(aS0 + (size_t)(tt) * 32, smem + bo_ + ldsA); \
        GLOAD_LDS16(aS1 + (size_t)(tt) * 32, smem + bo_ + ldsA + 8192); \
        GLOAD_LDS16(bS0 + (size_t)(tt) * 32, smem + bo_ + ldsB); } while (0)

    STAGE_P(0); STAGE_P(1); STAGE_P(2);
    asm volatile("s_waitcnt vmcnt(6)" ::: "memory");
    SBAR();
    #pragma unroll
    for (int i = 0; i < 4; ++i) afc[0][i] = *(const bf16x8*)(smem + ra + i * 1024);
    #pragma unroll
    for (int i = 0; i < 4; ++i) bfc[0][i] = *(const bf16x8*)(smem + rb + i * 1024);

    for (int tp = 0; tp < NT / 2; ++tp) {
        #pragma unroll
        for (int u = 0; u < 2; ++u) {
            const int t = 2 * tp + u;
            const int cn = ((t + 1) & 3) * 24576;
            if (t + 3 < NT) STAGE_P(t + 3);
            if (t < NT - 3)       asm volatile("s_waitcnt vmcnt(6)" ::: "memory");
            else if (t == NT - 3) asm volatile("s_waitcnt vmcnt(3)" ::: "memory");
            else if (t == NT - 2) asm volatile("s_waitcnt vmcnt(0)" ::: "memory");
            SBAR();
            #pragma unroll
            for (int i = 0; i < 4; ++i)
                afc[u ^ 1][i] = *(const bf16x8*)(smem + cn + ra + i * 1024);
            #pragma unroll
            for (int i = 0; i < 4; ++i)
                bfc[u ^ 1][i] = *(const bf16x8*)(smem + cn + rb + i * 1024);
            __builtin_amdgcn_s_setprio(1);
            #pragma unroll
            for (int mi = 0; mi < 4; ++mi)
                #pragma unroll
                for (int ni = 0; ni < 4; ++ni)
                    acc[mi][ni] = MFMA_BF16(afc[u][mi], bfc[u][ni], acc[mi][ni]);
            __builtin_amdgcn_s_setprio(0);
        }
    }
    #undef STAGE_P

    #pragma unroll
    for (int mi = 0; mi < 4; ++mi)
        #pragma unroll
        for (int ni = 0; ni < 4; ++ni)
            #pragma unroll
            for (int rr = 0; rr < 4; ++rr) {
                int m = m0 + wr * 64 + mi * 16 + quad * 4 + rr;
                int n = n0 + wc * 64 + ni * 16 + l15;
                outp[(size_t)m * 1024 + n] = acc[mi][ni][rr] + bias[n];
            }
}

// ---------------------------------------------------------------------------
// Flash attention (no-max softmax; Q pre-scaled so p = exp2(s) directly).
// Q: [bh][S][128]; Kg: [bh][S][128] chunk-swizzled (chunk^(s&15));
// Vg: [bh][128][S] (V^T); O: [B][S][H*128] bf16.
// Single 1024-block launch; bh->XCD grouping: all 16 mt-blocks of a bh get
// linear ids congruent mod 8 -> one XCD L2 serves its K/V re-reads.
// 4 waves; Q tile 128; KV tile 64 as two 32-kv halves; P round-trip is
// intra-wave; K/V staging double-buffered; 1 __syncthreads per kt.
#define LDS_BUFSZ 32768
#define LDS_VT    16384
#define LDS_PS    65536
__global__ __launch_bounds__(256, 2)
void attn_kernel(const __bf16* __restrict__ Q, const __bf16* __restrict__ Kg,
                 const __bf16* __restrict__ Vg, __bf16* __restrict__ O) {
    __shared__ __align__(16) char smem[73728];

    const int t = threadIdx.x;
    const int wave = t >> 6, lane = t & 63;
    const int l15 = lane & 15, quad = lane >> 4;

    // bh->XCD grouping decode (bijective over 1024 blocks = 64 bh x 16 mt)
    const int lin = blockIdx.x;
    const int mt = (lin >> 3) & 15;
    const int bh = ((lin >> 7) << 3) + (lin & 7);

    const int b = bh >> 4, h = bh & 15;
    const size_t base  = (size_t)bh * SS * DHH;
    const size_t vbase = (size_t)bh * DHH * SS;

    // K B-frag: addr = l15*256 + swz-chunk*16  (+4096*nl + 8192*hf + buf at use)
    int kaddr[4];
    #pragma unroll
    for (int kst = 0; kst < 4; ++kst)
        kaddr[kst] = l15 * 256 + (((4 * kst + quad) ^ l15) & 15) * 16;
    // Vt B-frag: row d = ds*16+l15 (imm 2048*ds), k-block = hf
    int vaddr[2];
    #pragma unroll
    for (int hf = 0; hf < 2; ++hf)
        vaddr[hf] = LDS_VT + l15 * 128 + (((4 * hf + quad) ^ (l15 & 7)) & 7) * 16;
    // Ps write base per nl: row = 32w+16ms+4q+rr -> +1024*ms+64*rr imm
    int pw[2];
    #pragma unroll
    for (int nl = 0; nl < 2; ++nl)
        pw[nl] = LDS_PS + (wave * 32 + quad * 4) * 64 +
                 (((2 * nl + (l15 >> 3)) ^ quad) & 3) * 16 + (l15 & 7) * 2;
    // Ps A-frag read base: row = 32w+16ms+l15 -> +1024*ms imm
    const int par = LDS_PS + (wave * 32 + l15) * 64 + ((quad ^ (l15 >> 2)) & 3) * 16;

    // staging source pointers (mt-independent)
    const __bf16* kstage = Kg + base + (size_t)wave * 2048 + lane * 8;
    const __bf16* vstage = Vg + vbase + (size_t)(wave * 32 + (lane >> 3)) * SS
                           + ((lane & 7) ^ ((lane >> 3) & 7)) * 8;

    // stage KV tile kt into buffer at byte offset bo (0 or LDS_BUFSZ)
    #define STAGE_KV(kt_, bo_) do { \
        _Pragma("unroll") \
        for (int i_ = 0; i_ < 4; ++i_) \
            GLOAD_LDS16(kstage + (size_t)(kt_) * 8192 + i_ * 512, \
                        smem + (bo_) + wave * 4096 + i_ * 1024); \
        _Pragma("unroll") \
        for (int i_ = 0; i_ < 4; ++i_) \
            GLOAD_LDS16(vstage + (kt_) * 64 + (size_t)i_ * 8 * SS, \
                        smem + (bo_) + LDS_VT + wave * 4096 + i_ * 1024); \
    } while (0)

    // Q fragments (A-operand), rows mt*128 + wave*32 + ms*16 + l15
    bf16x8 qf[2][4];
    #pragma unroll
    for (int ms = 0; ms < 2; ++ms) {
        int row = mt * 128 + wave * 32 + ms * 16 + l15;
        #pragma unroll
        for (int kst = 0; kst < 4; ++kst)
            qf[ms][kst] = *(const bf16x8*)(Q + base + (size_t)row * DHH + kst * 32 + quad * 8);
    }

    f32x4 oacc[2][8] = {};
    float li_[2][4] = {};

    STAGE_KV(0, 0);
    __syncthreads();   // drain stage(0)

    for (int kt = 0; kt < SS / 64; ++kt) {
        const int co = (kt & 1) * LDS_BUFSZ;
        if (kt + 1 < SS / 64) STAGE_KV(kt + 1, co ^ LDS_BUFSZ);

        #pragma unroll
        for (int hf = 0; hf < 2; ++hf) {
            // ---- QK for kv half hf (ns = 2hf, 2hf+1) ----
            f32x4 sx[2][2] = {};
            __builtin_amdgcn_s_setprio(1);
            #pragma unroll
            for (int kst = 0; kst < 4; ++kst) {
                bf16x8 kf0 = *(const bf16x8*)(smem + co + kaddr[kst] + 8192 * hf);
                bf16x8 kf1 = *(const bf16x8*)(smem + co + kaddr[kst] + 8192 * hf + 4096);
                sx[0][0] = MFMA_BF16(qf[0][kst], kf0, sx[0][0]);
                sx[1][0] = MFMA_BF16(qf[1][kst], kf0, sx[1][0]);
                sx[0][1] = MFMA_BF16(qf[0][kst], kf1, sx[0][1]);
                sx[1][1] = MFMA_BF16(qf[1][kst], kf1, sx[1][1]);
            }
            __builtin_amdgcn_s_setprio(0);
            // ---- p = exp2(s), row-sum partials ----
            #pragma unroll
            for (int ms = 0; ms < 2; ++ms)
                #pragma unroll
                for (int nl = 0; nl < 2; ++nl)
                    #pragma unroll
                    for (int rr = 0; rr < 4; ++rr) {
                        float p = EXP2(sx[ms][nl][rr]);
                        li_[ms][rr] += p;
                        sx[ms][nl][rr] = p;
                    }

            // ---- P-half -> LDS (intra-wave scratch, no barrier needed) ----
            #pragma unroll
            for (int ms = 0; ms < 2; ++ms)
                #pragma unroll
                for (int nl = 0; nl < 2; ++nl)
                    #pragma unroll
                    for (int rr = 0; rr < 4; ++rr)
                        *(__bf16*)(smem + pw[nl] + 1024 * ms + 64 * rr)
                            = (__bf16)sx[ms][nl][rr];

            // ---- O += P-half @ V-half ----
            bf16x8 pa0 = *(const bf16x8*)(smem + par);
            bf16x8 pa1 = *(const bf16x8*)(smem + par + 1024);
            __builtin_amdgcn_s_setprio(1);
            #pragma unroll
            for (int ds = 0; ds < 8; ++ds) {
                bf16x8 vf = *(const bf16x8*)(smem + co + vaddr[hf] + 2048 * ds);
                oacc[0][ds] = MFMA_BF16(pa0, vf, oacc[0][ds]);
                oacc[1][ds] = MFMA_BF16(pa1, vf, oacc[1][ds]);
            }
            __builtin_amdgcn_s_setprio(0);
        }
        // one barrier per kt: drains stage(kt+1) DMA (vmcnt) and orders all-wave
        // reads of buf(kt) before stage(kt+2) overwrites it next iteration
        __syncthreads();
    }
    #undef STAGE_KV

    // epilogue: reduce row-sums across the 16 lanes sharing a row
    #pragma unroll
    for (int ms = 0; ms < 2; ++ms)
        #pragma unroll
        for (int rr = 0; rr < 4; ++rr) {
            float v = li_[ms][rr];
            v += __shfl_xor(v, 1);
            v += __shfl_xor(v, 2);
            v += __shfl_xor(v, 4);
            v += __shfl_xor(v, 8);
            li_[ms][rr] = 1.f / v;
        }

    #pragma unroll
    for (int ms = 0; ms < 2; ++ms)
        #pragma unroll
        for (int rr = 0; rr < 4; ++rr) {
            int s = mt * 128 + wave * 32 + ms * 16 + quad * 4 + rr;
            size_t ob = ((size_t)b * SS + s) * (HH * DHH) + (size_t)h * DHH;
            #pragma unroll
            for (int ds = 0; ds < 8; ++ds)
                O[ob + ds * 16 + l15] = (__bf16)(oacc[ms][ds][rr] * li_[ms][rr]);
        }
}

// ---------------------------------------------------------------------------
extern "C" void kernel_launch(void* const* d_in, const int* in_sizes, int n_in,
                              void* d_out, int out_size, void* d_ws, size_t ws_size,
                              hipStream_t stream) {
    const float* x      = (const float*)d_in[0];
    const float* c      = (const float*)d_in[1];
    const float* Wq_x   = (const float*)d_in[2];
    const float* Wk_x   = (const float*)d_in[3];
    const float* Wv_x   = (const float*)d_in[4];
    const float* Wq_c   = (const float*)d_in[5];
    const float* Wk_c   = (const float*)d_in[6];
    const float* Wv_c   = (const float*)d_in[7];
    const float* W_proj = (const float*)d_in[8];
    const float* b_proj = (const float*)d_in[9];

    const size_t nXC  = (size_t)BB * SS * DD;
    const size_t nW   = (size_t)DD * DD;
    const size_t nWP  = (size_t)(2 * HH * 64) * DD;
    const size_t nQKV = (size_t)BB * HH * SS * DHH;

    __bf16* ws  = (__bf16*)d_ws;
    __bf16* xb  = ws;
    __bf16* cb  = xb + nXC;
    __bf16* wt0 = cb + nXC;          // [Wq_x; Wk_x; Wv_x; Wq_c; Wk_c; Wv_c]^T contiguous
    __bf16* wt2 = wt0 + 2 * nW;      // Wv_x^T
    __bf16* wt3 = wt0 + 3 * nW;      // Wq_c^T (c's Q,K pair start)
    __bf16* wt5 = wt0 + 5 * nW;      // Wv_c^T
    __bf16* wtp = wt0 + 6 * nW;      // W_proj^T [1024][2048]
    __bf16* Qb  = wtp + nWP;
    __bf16* Kb  = Qb + nQKV;         // MUST stay at Qb + nQKV (EPI4 assumes it)
    __bf16* Vb  = Kb + nQKV;         // [B*H][128][S] pre-transposed
    __bf16* Ob  = xb;                // alias x/c region (dead after QKV GEMMs)

    cast2_kernel<<<(int)(2 * nXC / 1024), 256, 0, stream>>>(x, c, xb, (int)nXC);

    transpose6_kernel<<<dim3(32, 32, 6), dim3(32, 8), 0, stream>>>(
        Wq_x, Wk_x, Wv_x, Wq_c, Wk_c, Wv_c, wt0);
    transpose_cast_kernel<<<dim3(32, 64), dim3(32, 8), 0, stream>>>(W_proj, wtp, 2048, 1024);

    // z-batched fused Q+K GEMMs (M=8192, N=2048, K=1024): z=0 x-path, z=1 c-path
    gemm256_kernel<4><<<dim3(32, 8, 2), 512, 0, stream>>>(xb, cb, wt0, wt3, 1024, Qb, nullptr);
    // z-batched V GEMMs (A = Wv^T, B = activations) -> V^T [bh][d][s]
    gemm256_kernel<2><<<dim3(4, 32, 2), 512, 0, stream>>>(wt2, wt5, xb, cb, 1024, Vb, nullptr);

    // attention (writes Ob = [B,S,H*128] bf16), single launch, bh->XCD grouping
    attn_kernel<<<dim3(1024), 256, 0, stream>>>(Qb, Kb, Vb, Ob);

    // projection (M=8192, K=2048, N=1024) + bias -> fp32 out, 256x128 tile
    gemm_proj_kernel<<<dim3(32, 8), 512, 0, stream>>>(Ob, wtp, 2048, (float*)d_out, b_proj);
}

// Round 7
// 447.280 us; speedup vs baseline: 1.0902x; 1.0005x over previous
//
#include <hip/hip_runtime.h>
#include <hip/hip_bf16.h>
#include <stdint.h>

// Problem constants
#define BB 4
#define SS 2048
#define DD 1024
#define HH 16
#define DHH 128   // per-head dim after concat (2*64)

typedef __bf16 bf16x8 __attribute__((ext_vector_type(8)));
typedef __bf16 bf16x4 __attribute__((ext_vector_type(4)));
typedef float  f32x4  __attribute__((ext_vector_type(4)));

// (1/sqrt(64)) * log2(e), folded into Q at GEMM epilogue time
#define SL2E 0.180336880111186f

#if __has_builtin(__builtin_amdgcn_exp2f)
#define EXP2(x) __builtin_amdgcn_exp2f(x)
#else
#define EXP2(x) exp2f(x)
#endif

// async global->LDS, 16B per lane; LDS dest is wave-uniform base + lane*16,
// global src is per-lane (gather allowed)
#define GLOAD_LDS16(gp, lp) \
  __builtin_amdgcn_global_load_lds((const __attribute__((address_space(1))) unsigned int*)(gp), \
                                   (__attribute__((address_space(3))) unsigned int*)(lp), 16, 0, 0)

// compiler memory fence around raw s_barrier so LDS ops can't be moved across
#define SBAR() do { asm volatile("" ::: "memory"); \
                    __builtin_amdgcn_s_barrier();  \
                    asm volatile("" ::: "memory"); } while (0)

#define MFMA_BF16(a, b, c) __builtin_amdgcn_mfma_f32_16x16x32_bf16((a), (b), (c), 0, 0, 0)

// ---------------------------------------------------------------------------
// Fused cast of x and c -> bf16 (dest xb and cb are contiguous)
__global__ void cast2_kernel(const float* __restrict__ x, const float* __restrict__ c,
                             __bf16* __restrict__ out, int n) {
    int i = (blockIdx.x * blockDim.x + threadIdx.x) * 4;
    const float* src = (i < n) ? (x + i) : (c + (i - n));
    f32x4 v = *(const f32x4*)src;
    bf16x4 o;
    o[0] = (__bf16)v[0]; o[1] = (__bf16)v[1]; o[2] = (__bf16)v[2]; o[3] = (__bf16)v[3];
    *(bf16x4*)(out + i) = o;
}

// ---------------------------------------------------------------------------
// Transpose + cast: W[K][N] fp32 -> Wt[N][K] bf16 (used for W_proj)
__global__ void transpose_cast_kernel(const float* __restrict__ in, __bf16* __restrict__ out,
                                      int K, int N) {
    __shared__ float tile[32][33];
    int n0 = blockIdx.x * 32, k0 = blockIdx.y * 32;
    int tx = threadIdx.x, ty = threadIdx.y;   // 32 x 8
    #pragma unroll
    for (int i = 0; i < 32; i += 8)
        tile[ty + i][tx] = in[(size_t)(k0 + ty + i) * N + n0 + tx];
    __syncthreads();
    #pragma unroll
    for (int i = 0; i < 32; i += 8)
        out[(size_t)(n0 + ty + i) * K + k0 + tx] = (__bf16)tile[tx][ty + i];
}

// Fused transpose+cast of the six 1024x1024 QKV weights into contiguous dst
// Order: Wq_x, Wk_x, Wv_x, Wq_c, Wk_c, Wv_c  (Q,K adjacent per input for fusion)
__global__ void transpose6_kernel(const float* s0, const float* s1, const float* s2,
                                  const float* s3, const float* s4, const float* s5,
                                  __bf16* __restrict__ dst) {
    const float* srcs[6] = {s0, s1, s2, s3, s4, s5};
    const float* __restrict__ in = srcs[blockIdx.z];
    __bf16* __restrict__ out = dst + (size_t)blockIdx.z * 1024 * 1024;
    __shared__ float tile[32][33];
    int n0 = blockIdx.x * 32, k0 = blockIdx.y * 32;
    int tx = threadIdx.x, ty = threadIdx.y;   // 32 x 8
    #pragma unroll
    for (int i = 0; i < 32; i += 8)
        tile[ty + i][tx] = in[(size_t)(k0 + ty + i) * 1024 + n0 + tx];
    __syncthreads();
    #pragma unroll
    for (int i = 0; i < 32; i += 8)
        out[(size_t)(n0 + ty + i) * 1024 + k0 + tx] = (__bf16)tile[tx][ty + i];
}

// ---------------------------------------------------------------------------
// 256x256 pipelined GEMM: C = A @ Bt^T (bf16, both contiguous in K).
// 512 threads = 8 waves (2x4), per-wave 128x64 output (acc 8x4).
// BK=32; LDS ring of 4 x 32KB; staging 3 tiles ahead (global_load_lds).
// Fragments read ONE PHASE AHEAD of their MFMA (LDS service overlaps the
// previous MFMA cluster); next-tile reads AFTER the barrier that follows the
// counted vmcnt. vmcnt never drains to 0 until the 2-tile epilogue.
template <int EPI>
__global__ __launch_bounds__(512, 2)
void gemm256_kernel(const __bf16* __restrict__ A0, const __bf16* __restrict__ A1,
                    const __bf16* __restrict__ B0, const __bf16* __restrict__ B1,
                    int K, void* __restrict__ outp, const float* __restrict__ bias) {
    const int z = blockIdx.z;
    const __bf16* __restrict__ A  = z ? A1 : A0;
    const __bf16* __restrict__ Bt = z ? B1 : B0;
    const int qkv_off = z * 64;

    __shared__ __align__(16) char smem[131072];   // 4 x (A 16KB @0 + B 16KB @16384)

    const int tid = threadIdx.x;
    const int wave = tid >> 6, lane = tid & 63;
    const int l15 = lane & 15, quad = lane >> 4;
    const int wr = wave >> 2, wc = wave & 3;      // wave -> (row half, col quarter)

    // XCD-aware block remap (bijective: nwg per z is a multiple of 8)
    const int gx = gridDim.x;
    const int nwg = gx * gridDim.y;
    const int hwl = blockIdx.y * gx + blockIdx.x;
    const int lg  = (hwl & 7) * (nwg >> 3) + (hwl >> 3);
    const int m0 = (lg % gx) * 256, n0 = (lg / gx) * 256;

    // staging: thread tid covers (r = j*128 + tid/4, chunk = tid&3), j=0,1
    // global source chunk pre-swizzled: c_src = (tid&3) ^ ((r>>2)&3)
    const int rA = tid >> 2;
    const int cs = (tid & 3) ^ ((tid >> 4) & 3);
    const __bf16* aS0 = A  + (size_t)(m0 + rA) * K + cs * 8;
    const __bf16* aS1 = aS0 + (size_t)128 * K;
    const __bf16* bS0 = Bt + (size_t)(n0 + rA) * K + cs * 8;
    const __bf16* bS1 = bS0 + (size_t)128 * K;
    const int ldsA = wave * 1024;            // + j*8192 + buf*32768 (lane*16 by HW)
    const int ldsB = 16384 + wave * 1024;

    // ds_read bases: row r, byte = r*64 + ((quad ^ ((r>>2)&3))&3)*16
    const int swz = ((quad ^ (l15 >> 2)) & 3) * 16;
    const int ra = (wr * 128 + l15) * 64 + swz;            // + mi*1024 + buf
    const int rb = 16384 + (wc * 64 + l15) * 64 + swz;     // + ni*1024 + buf

    f32x4 acc[8][4] = {};
    bf16x8 afc[2][4], bfc[2][4], afB[4];
    const int NT = K >> 5;

    #define STAGE_A(tt) do { const int bo_ = ((tt) & 3) * 32768; \
        GLOAD_LDS16(aS0 + (size_t)(tt) * 32, smem + bo_ + ldsA); \
        GLOAD_LDS16(aS1 + (size_t)(tt) * 32, smem + bo_ + ldsA + 8192); } while (0)
    #define STAGE_B(tt) do { const int bo_ = ((tt) & 3) * 32768; \
        GLOAD_LDS16(bS0 + (size_t)(tt) * 32, smem + bo_ + ldsB); \
        GLOAD_LDS16(bS1 + (size_t)(tt) * 32, smem + bo_ + ldsB + 8192); } while (0)

    // prologue: stage tiles 0..2; wait tile 0 (8 younger in flight); read set0
    STAGE_A(0); STAGE_B(0);
    STAGE_A(1); STAGE_B(1);
    STAGE_A(2); STAGE_B(2);
    asm volatile("s_waitcnt vmcnt(8)" ::: "memory");
    SBAR();
    #pragma unroll
    for (int i = 0; i < 4; ++i) afc[0][i] = *(const bf16x8*)(smem + ra + i * 1024);
    #pragma unroll
    for (int i = 0; i < 4; ++i) bfc[0][i] = *(const bf16x8*)(smem + rb + i * 1024);

    for (int tp = 0; tp < NT / 2; ++tp) {
        #pragma unroll
        for (int u = 0; u < 2; ++u) {
            const int t = 2 * tp + u;
            const int co = (t & 3) * 32768;
            const int cn = ((t + 1) & 3) * 32768;
            // ---------------- phase 1 ----------------
            #pragma unroll
            for (int i = 0; i < 4; ++i)
                afB[i] = *(const bf16x8*)(smem + co + ra + (4 + i) * 1024);
            if (t + 3 < NT) STAGE_A(t + 3);
            SBAR();
            __builtin_amdgcn_s_setprio(1);
            #pragma unroll
            for (int mi = 0; mi < 4; ++mi)
                #pragma unroll
                for (int ni = 0; ni < 4; ++ni)
                    acc[mi][ni] = MFMA_BF16(afc[u][mi], bfc[u][ni], acc[mi][ni]);
            __builtin_amdgcn_s_setprio(0);
            // ---------------- phase 2 ----------------
            if (t + 3 < NT) STAGE_B(t + 3);
            if (t < NT - 3)       asm volatile("s_waitcnt vmcnt(8)" ::: "memory");
            else if (t == NT - 3) asm volatile("s_waitcnt vmcnt(4)" ::: "memory");
            else if (t == NT - 2) asm volatile("s_waitcnt vmcnt(0)" ::: "memory");
            SBAR();
            #pragma unroll
            for (int i = 0; i < 4; ++i)
                afc[u ^ 1][i] = *(const bf16x8*)(smem + cn + ra + i * 1024);
            #pragma unroll
            for (int i = 0; i < 4; ++i)
                bfc[u ^ 1][i] = *(const bf16x8*)(smem + cn + rb + i * 1024);
            __builtin_amdgcn_s_setprio(1);
            #pragma unroll
            for (int mi = 0; mi < 4; ++mi)
                #pragma unroll
                for (int ni = 0; ni < 4; ++ni)
                    acc[4 + mi][ni] = MFMA_BF16(afB[mi], bfc[u][ni], acc[4 + mi][ni]);
            __builtin_amdgcn_s_setprio(0);
        }
    }
    #undef STAGE_A
    #undef STAGE_B

    const size_t nQKV = (size_t)BB * HH * SS * DHH;
    #pragma unroll
    for (int mi = 0; mi < 8; ++mi) {
        #pragma unroll
        for (int ni = 0; ni < 4; ++ni) {
            #pragma unroll
            for (int rr = 0; rr < 4; ++rr) {
                int m = m0 + wr * 128 + mi * 16 + quad * 4 + rr;
                int n = n0 + wc * 64 + ni * 16 + l15;
                if (EPI == 2) {
                    int h = m >> 6, dl = m & 63;
                    int b = n >> 11, s = n & (SS - 1);
                    __bf16* vt = (__bf16*)outp;
                    vt[(((size_t)b * HH + h) * DHH + dl + qkv_off) * SS + s] = (__bf16)acc[mi][ni][rr];
                } else {  // EPI 4
                    int b = m >> 11, s = m & (SS - 1);
                    int n1 = n & 1023;
                    int h = n1 >> 6, d = (n1 & 63) + qkv_off;
                    if (n < 1024) {
                        __bf16* q = (__bf16*)outp;
                        q[(((size_t)b * HH + h) * SS + s) * DHH + d] = (__bf16)(acc[mi][ni][rr] * SL2E);
                    } else {
                        int dsw = (((d >> 3) ^ (s & 15)) << 3) | (d & 7);
                        __bf16* kq = (__bf16*)outp + nQKV;
                        kq[(((size_t)b * HH + h) * SS + s) * DHH + dsw] = (__bf16)acc[mi][ni][rr];
                    }
                }
            }
        }
    }
}

// ---------------------------------------------------------------------------
// Projection GEMM: C = A @ Bt^T + bias, fp32 out.
// Tile 256x128 -> grid 32x8 = 256 blocks (full chip).
// 512 threads = 8 waves (4x2), per-wave 64x64 (acc 4x4 = 64 regs).
// Same pipelined pattern, single phase per tile. Ring-4 x 24KB LDS.
__global__ __launch_bounds__(512, 2)
void gemm_proj_kernel(const __bf16* __restrict__ A, const __bf16* __restrict__ Bt,
                      int K, float* __restrict__ outp, const float* __restrict__ bias) {
    __shared__ __align__(16) char smem[98304];    // 4 x (A 16KB @0 + B 8KB @16384)

    const int tid = threadIdx.x;
    const int wave = tid >> 6, lane = tid & 63;
    const int l15 = lane & 15, quad = lane >> 4;
    const int wr = wave >> 1, wc = wave & 1;      // 4 row-strips x 2 col-halves

    // XCD-aware remap (nwg = 256, multiple of 8)
    const int gx = gridDim.x;
    const int nwg = gx * gridDim.y;
    const int hwl = blockIdx.y * gx + blockIdx.x;
    const int lg  = (hwl & 7) * (nwg >> 3) + (hwl >> 3);
    const int m0 = (lg % gx) * 256, n0 = (lg / gx) * 128;

    const int rA = tid >> 2;
    const int cs = (tid & 3) ^ ((tid >> 4) & 3);
    const __bf16* aS0 = A  + (size_t)(m0 + rA) * K + cs * 8;
    const __bf16* aS1 = aS0 + (size_t)128 * K;
    const __bf16* bS0 = Bt + (size_t)(n0 + rA) * K + cs * 8;   // rA < 128 covers all B rows
    const int ldsA = wave * 1024;
    const int ldsB = 16384 + wave * 1024;

    const int swz = ((quad ^ (l15 >> 2)) & 3) * 16;
    const int ra = (wr * 64 + l15) * 64 + swz;             // + mi*1024 + buf
    const int rb = 16384 + (wc * 64 + l15) * 64 + swz;     // + ni*1024 + buf

    f32x4 acc[4][4] = {};
    bf16x8 afc[2][4], bfc[2][4];
    const int NT = K >> 5;

    #define STAGE_P(tt) do { const int bo_ = ((tt) & 3) * 24576; \
        GLOAD_LDS16(aS0 + (size_t)(tt) * 32, smem + bo_ + ldsA); \
        GLOAD_LDS16(aS1 + (size_t)(tt) * 32, smem + bo_ + ldsA + 8192); \
        GLOAD_LDS16(bS0 + (size_t)(tt) * 32, smem + bo_ + ldsB); } while (0)

    STAGE_P(0); STAGE_P(1); STAGE_P(2);
    asm volatile("s_waitcnt vmcnt(6)" ::: "memory");
    SBAR();
    #pragma unroll
    for (int i = 0; i < 4; ++i) afc[0][i] = *(const bf16x8*)(smem + ra + i * 1024);
    #pragma unroll
    for (int i = 0; i < 4; ++i) bfc[0][i] = *(const bf16x8*)(smem + rb + i * 1024);

    for (int tp = 0; tp < NT / 2; ++tp) {
        #pragma unroll
        for (int u = 0; u < 2; ++u) {
            const int t = 2 * tp + u;
            const int cn = ((t + 1) & 3) * 24576;
            if (t + 3 < NT) STAGE_P(t + 3);
            if (t < NT - 3)       asm volatile("s_waitcnt vmcnt(6)" ::: "memory");
            else if (t == NT - 3) asm volatile("s_waitcnt vmcnt(3)" ::: "memory");
            else if (t == NT - 2) asm volatile("s_waitcnt vmcnt(0)" ::: "memory");
            SBAR();
            #pragma unroll
            for (int i = 0; i < 4; ++i)
                afc[u ^ 1][i] = *(const bf16x8*)(smem + cn + ra + i * 1024);
            #pragma unroll
            for (int i = 0; i < 4; ++i)
                bfc[u ^ 1][i] = *(const bf16x8*)(smem + cn + rb + i * 1024);
            __builtin_amdgcn_s_setprio(1);
            #pragma unroll
            for (int mi = 0; mi < 4; ++mi)
                #pragma unroll
                for (int ni = 0; ni < 4; ++ni)
                    acc[mi][ni] = MFMA_BF16(afc[u][mi], bfc[u][ni], acc[mi][ni]);
            __builtin_amdgcn_s_setprio(0);
        }
    }
    #undef STAGE_P

    #pragma unroll
    for (int mi = 0; mi < 4; ++mi)
        #pragma unroll
        for (int ni = 0; ni < 4; ++ni)
            #pragma unroll
            for (int rr = 0; rr < 4; ++rr) {
                int m = m0 + wr * 64 + mi * 16 + quad * 4 + rr;
                int n = n0 + wc * 64 + ni * 16 + l15;
                outp[(size_t)m * 1024 + n] = acc[mi][ni][rr] + bias[n];
            }
}

// ---------------------------------------------------------------------------
// Flash attention (no-max softmax; Q pre-scaled so p = exp2(s) directly).
// Q: [bh][S][128]; Kg: [bh][S][128] chunk-swizzled (chunk^(s&15));
// Vg: [bh][128][S] (V^T); O: [B][S][H*128] bf16.
// ROUND-7: Q tile 256 (64 rows/wave, ms=4) -> 512 blocks. K/V LDS reads per
// Q-row drop 44% (attn is LDS-throughput-bound: 36 b128/32rows -> 40/64).
// QK processes one kv-column-block (nl) at a time to cap live VGPRs (sxn[4]).
// Ps loses its hf dim (same rows overwritten per half; intra-wave only).
// LDS 80 KB: buf[2] x { Ks 16KB, Vt 16KB } @0, Ps [256][64B] @65536.
// 2 blocks/CU = exactly 160 KiB. bh->XCD grouping (512 = 64 bh x 8 mt).
#define LDS_BUFSZ 32768
#define LDS_VT    16384
#define LDS_PS    65536
__global__ __launch_bounds__(256, 2)
void attn_kernel(const __bf16* __restrict__ Q, const __bf16* __restrict__ Kg,
                 const __bf16* __restrict__ Vg, __bf16* __restrict__ O) {
    __shared__ __align__(16) char smem[81920];

    const int t = threadIdx.x;
    const int wave = t >> 6, lane = t & 63;
    const int l15 = lane & 15, quad = lane >> 4;

    // bh->XCD grouping decode (bijective over 512 blocks = 64 bh x 8 mt)
    const int lin = blockIdx.x;
    const int mt = (lin >> 3) & 7;
    const int bh = ((lin >> 6) << 3) + (lin & 7);

    const int b = bh >> 4, h = bh & 15;
    const size_t base  = (size_t)bh * SS * DHH;
    const size_t vbase = (size_t)bh * DHH * SS;

    // K B-frag: addr = l15*256 + swz-chunk*16  (+4096*nl + 8192*hf + buf at use)
    int kaddr[4];
    #pragma unroll
    for (int kst = 0; kst < 4; ++kst)
        kaddr[kst] = l15 * 256 + (((4 * kst + quad) ^ l15) & 15) * 16;
    // Vt B-frag: row d = ds*16+l15 (imm 2048*ds), k-block = hf
    int vaddr[2];
    #pragma unroll
    for (int hf = 0; hf < 2; ++hf)
        vaddr[hf] = LDS_VT + l15 * 128 + (((4 * hf + quad) ^ (l15 & 7)) & 7) * 16;
    // Ps write base per nl: row = 64w+16ms+4q+rr -> +1024*ms+64*rr imm
    int pw[2];
    #pragma unroll
    for (int nl = 0; nl < 2; ++nl)
        pw[nl] = LDS_PS + (wave * 64 + quad * 4) * 64 +
                 (((2 * nl + (l15 >> 3)) ^ quad) & 3) * 16 + (l15 & 7) * 2;
    // Ps A-frag read base: row = 64w+16ms+l15 -> +1024*ms imm
    const int par = LDS_PS + (wave * 64 + l15) * 64 + ((quad ^ (l15 >> 2)) & 3) * 16;

    // staging source pointers (mt-independent)
    const __bf16* kstage = Kg + base + (size_t)wave * 2048 + lane * 8;
    const __bf16* vstage = Vg + vbase + (size_t)(wave * 32 + (lane >> 3)) * SS
                           + ((lane & 7) ^ ((lane >> 3) & 7)) * 8;

    // stage KV tile kt into buffer at byte offset bo (0 or LDS_BUFSZ)
    #define STAGE_KV(kt_, bo_) do { \
        _Pragma("unroll") \
        for (int i_ = 0; i_ < 4; ++i_) \
            GLOAD_LDS16(kstage + (size_t)(kt_) * 8192 + i_ * 512, \
                        smem + (bo_) + wave * 4096 + i_ * 1024); \
        _Pragma("unroll") \
        for (int i_ = 0; i_ < 4; ++i_) \
            GLOAD_LDS16(vstage + (kt_) * 64 + (size_t)i_ * 8 * SS, \
                        smem + (bo_) + LDS_VT + wave * 4096 + i_ * 1024); \
    } while (0)

    // Q fragments (A-operand), rows mt*256 + wave*64 + ms*16 + l15
    bf16x8 qf[4][4];
    #pragma unroll
    for (int ms = 0; ms < 4; ++ms) {
        int row = mt * 256 + wave * 64 + ms * 16 + l15;
        #pragma unroll
        for (int kst = 0; kst < 4; ++kst)
            qf[ms][kst] = *(const bf16x8*)(Q + base + (size_t)row * DHH + kst * 32 + quad * 8);
    }

    f32x4 oacc[4][8] = {};
    float li_[4][4] = {};

    STAGE_KV(0, 0);
    __syncthreads();   // drain stage(0)

    for (int kt = 0; kt < SS / 64; ++kt) {
        const int co = (kt & 1) * LDS_BUFSZ;
        if (kt + 1 < SS / 64) STAGE_KV(kt + 1, co ^ LDS_BUFSZ);

        #pragma unroll
        for (int hf = 0; hf < 2; ++hf) {
            // ---- QK for kv half hf, one nl column-block at a time ----
            #pragma unroll
            for (int nl = 0; nl < 2; ++nl) {
                f32x4 sxn[4] = {};
                __builtin_amdgcn_s_setprio(1);
                #pragma unroll
                for (int kst = 0; kst < 4; ++kst) {
                    bf16x8 kf = *(const bf16x8*)(smem + co + kaddr[kst] + 8192 * hf + 4096 * nl);
                    sxn[0] = MFMA_BF16(qf[0][kst], kf, sxn[0]);
                    sxn[1] = MFMA_BF16(qf[1][kst], kf, sxn[1]);
                    sxn[2] = MFMA_BF16(qf[2][kst], kf, sxn[2]);
                    sxn[3] = MFMA_BF16(qf[3][kst], kf, sxn[3]);
                }
                __builtin_amdgcn_s_setprio(0);
                // p = exp2(s), row-sum partials, P write (intra-wave scratch)
                #pragma unroll
                for (int ms = 0; ms < 4; ++ms)
                    #pragma unroll
                    for (int rr = 0; rr < 4; ++rr) {
                        float p = EXP2(sxn[ms][rr]);
                        li_[ms][rr] += p;
                        *(__bf16*)(smem + pw[nl] + 1024 * ms + 64 * rr) = (__bf16)p;
                    }
            }

            // ---- O += P-half @ V-half ----
            bf16x8 pa[4];
            #pragma unroll
            for (int ms = 0; ms < 4; ++ms)
                pa[ms] = *(const bf16x8*)(smem + par + 1024 * ms);
            __builtin_amdgcn_s_setprio(1);
            #pragma unroll
            for (int ds = 0; ds < 8; ++ds) {
                bf16x8 vf = *(const bf16x8*)(smem + co + vaddr[hf] + 2048 * ds);
                oacc[0][ds] = MFMA_BF16(pa[0], vf, oacc[0][ds]);
                oacc[1][ds] = MFMA_BF16(pa[1], vf, oacc[1][ds]);
                oacc[2][ds] = MFMA_BF16(pa[2], vf, oacc[2][ds]);
                oacc[3][ds] = MFMA_BF16(pa[3], vf, oacc[3][ds]);
            }
            __builtin_amdgcn_s_setprio(0);
        }
        // one barrier per kt: drains stage(kt+1) DMA (vmcnt) and orders all-wave
        // reads of buf(kt) before stage(kt+2) overwrites it next iteration
        __syncthreads();
    }
    #undef STAGE_KV

    // epilogue: reduce row-sums across the 16 lanes sharing a row
    #pragma unroll
    for (int ms = 0; ms < 4; ++ms)
        #pragma unroll
        for (int rr = 0; rr < 4; ++rr) {
            float v = li_[ms][rr];
            v += __shfl_xor(v, 1);
            v += __shfl_xor(v, 2);
            v += __shfl_xor(v, 4);
            v += __shfl_xor(v, 8);
            li_[ms][rr] = 1.f / v;
        }

    #pragma unroll
    for (int ms = 0; ms < 4; ++ms)
        #pragma unroll
        for (int rr = 0; rr < 4; ++rr) {
            int s = mt * 256 + wave * 64 + ms * 16 + quad * 4 + rr;
            size_t ob = ((size_t)b * SS + s) * (HH * DHH) + (size_t)h * DHH;
            #pragma unroll
            for (int ds = 0; ds < 8; ++ds)
                O[ob + ds * 16 + l15] = (__bf16)(oacc[ms][ds][rr] * li_[ms][rr]);
        }
}

// ---------------------------------------------------------------------------
extern "C" void kernel_launch(void* const* d_in, const int* in_sizes, int n_in,
                              void* d_out, int out_size, void* d_ws, size_t ws_size,
                              hipStream_t stream) {
    const float* x      = (const float*)d_in[0];
    const float* c      = (const float*)d_in[1];
    const float* Wq_x   = (const float*)d_in[2];
    const float* Wk_x   = (const float*)d_in[3];
    const float* Wv_x   = (const float*)d_in[4];
    const float* Wq_c   = (const float*)d_in[5];
    const float* Wk_c   = (const float*)d_in[6];
    const float* Wv_c   = (const float*)d_in[7];
    const float* W_proj = (const float*)d_in[8];
    const float* b_proj = (const float*)d_in[9];

    const size_t nXC  = (size_t)BB * SS * DD;
    const size_t nW   = (size_t)DD * DD;
    const size_t nWP  = (size_t)(2 * HH * 64) * DD;
    const size_t nQKV = (size_t)BB * HH * SS * DHH;

    __bf16* ws  = (__bf16*)d_ws;
    __bf16* xb  = ws;
    __bf16* cb  = xb + nXC;
    __bf16* wt0 = cb + nXC;          // [Wq_x; Wk_x; Wv_x; Wq_c; Wk_c; Wv_c]^T contiguous
    __bf16* wt2 = wt0 + 2 * nW;      // Wv_x^T
    __bf16* wt3 = wt0 + 3 * nW;      // Wq_c^T (c's Q,K pair start)
    __bf16* wt5 = wt0 + 5 * nW;      // Wv_c^T
    __bf16* wtp = wt0 + 6 * nW;      // W_proj^T [1024][2048]
    __bf16* Qb  = wtp + nWP;
    __bf16* Kb  = Qb + nQKV;         // MUST stay at Qb + nQKV (EPI4 assumes it)
    __bf16* Vb  = Kb + nQKV;         // [B*H][128][S] pre-transposed
    __bf16* Ob  = xb;                // alias x/c region (dead after QKV GEMMs)

    cast2_kernel<<<(int)(2 * nXC / 1024), 256, 0, stream>>>(x, c, xb, (int)nXC);

    transpose6_kernel<<<dim3(32, 32, 6), dim3(32, 8), 0, stream>>>(
        Wq_x, Wk_x, Wv_x, Wq_c, Wk_c, Wv_c, wt0);
    transpose_cast_kernel<<<dim3(32, 64), dim3(32, 8), 0, stream>>>(W_proj, wtp, 2048, 1024);

    // z-batched fused Q+K GEMMs (M=8192, N=2048, K=1024): z=0 x-path, z=1 c-path
    gemm256_kernel<4><<<dim3(32, 8, 2), 512, 0, stream>>>(xb, cb, wt0, wt3, 1024, Qb, nullptr);
    // z-batched V GEMMs (A = Wv^T, B = activations) -> V^T [bh][d][s]
    gemm256_kernel<2><<<dim3(4, 32, 2), 512, 0, stream>>>(wt2, wt5, xb, cb, 1024, Vb, nullptr);

    // attention (writes Ob = [B,S,H*128] bf16), Q tile 256 -> 512 blocks
    attn_kernel<<<dim3(512), 256, 0, stream>>>(Qb, Kb, Vb, Ob);

    // projection (M=8192, K=2048, N=1024) + bias -> fp32 out, 256x128 tile
    gemm_proj_kernel<<<dim3(32, 8), 512, 0, stream>>>(Ob, wtp, 2048, (float*)d_out, b_proj);
}